// Round 10
// baseline (1908.469 us; speedup 1.0000x reference)
//
#include <hip/hip_runtime.h>

typedef unsigned short u16;
typedef __bf16 bf16x8 __attribute__((ext_vector_type(8)));
typedef float f32x4 __attribute__((ext_vector_type(4)));
typedef u16 u16x4 __attribute__((ext_vector_type(4)));

#define DEVI static __device__ __forceinline__

DEVI u16 f2bf(float f){
  unsigned u = __float_as_uint(f);
  u += 0x7FFFu + ((u >> 16) & 1u);
  return (u16)(u >> 16);
}

DEVI f32x4 mfma16(bf16x8 a, bf16x8 b, f32x4 c){
  return __builtin_amdgcn_mfma_f32_16x16x32_bf16(a, b, c, 0, 0, 0);
}

DEVI void gld16(u16* lds, const u16* g){
  __builtin_amdgcn_global_load_lds(
      (const __attribute__((address_space(1))) void*)g,
      (__attribute__((address_space(3))) void*)lds, 16, 0, 0);
}

// ---------------- fp32 -> bf16 convert ----------------
__global__ void cvt_bf16(const float* __restrict__ s, u16* __restrict__ d, int n4){
  int i = blockIdx.x * blockDim.x + threadIdx.x;
  int stride = gridDim.x * blockDim.x;
  for (; i < n4; i += stride){
    float4 v = *(const float4*)(s + (size_t)i * 4);
    u16x4 o = { f2bf(v.x), f2bf(v.y), f2bf(v.z), f2bf(v.w) };
    *(u16x4*)(d + (size_t)i * 4) = o;
  }
}

// ---------------- GEMM: C = A * Bm^T + bias ----------------
// 256x256 tile, BK=32, 1024 threads (16 waves 4Mx4N, each 64x64 out).
// TWO 32KB LDS buffers (64 KB) -> 2 BLOCKS/CU (m114: independent barrier
// groups overlap MFMA with the sibling block's barrier/drain stalls —
// R9's 1-block/CU 16-wave config stalled ~50% at correlated barriers).
// Lead-1 double-buffer, counted vmcnt(2) (tile t's loads landed, t+1's
// stay in flight; never 0 mid-loop). Two barriers/tile (stage target must
// be reader-free; sibling block covers the cost).
// __launch_bounds__(1024, 8): 8 waves/EU -> VGPR cap 64 (R9 measured 60).
// Fat-row swizzle (128B rows, 16B chunk ^= fatrow&7): linear gld_lds dest
// + inverse-swizzled global source + swizzled ds_read (conflicts = 0).
// MODE 0: QKV epilogue (Q,K row-major bf16; V transposed per-window).
// MODE 1: fp32 store + bias.
template<int MODE>
__global__ __launch_bounds__(1024, 8)
void gemm_bt(const u16* __restrict__ A, const u16* __restrict__ Bm,
             const float* __restrict__ bias,
             u16* __restrict__ Qws, u16* __restrict__ Kws, u16* __restrict__ Vtws,
             float* __restrict__ Cf)
{
  constexpr int K = 1024;
  constexpr int NT = K / 32;                       // 32 K-tiles
  __shared__ __align__(16) u16 lds[2 * 16384];     // 64 KiB (A 16KB + B 16KB per buf)
  const int t = threadIdx.x;
  const int w = t >> 6, l = t & 63, g = l >> 4, r16 = l & 15;
  const int wm = w >> 2, wn = w & 3;               // 4Mx4N wave grid

  // XCD-bijective block swizzle (nwg % 8 == 0 in both modes)
  constexpr int NBX = (MODE == 0) ? 12 : 4;
  constexpr int NWG = NBX * 64;
  const int orig = blockIdx.y * NBX + blockIdx.x;
  const int swzb = (orig & 7) * (NWG >> 3) + (orig >> 3);
  const int row0 = (swzb / NBX) * 256, col0 = (swzb % NBX) * 256;

  const f32x4 zero = {0.f, 0.f, 0.f, 0.f};
  f32x4 acc[4][4];
#pragma unroll
  for (int m = 0; m < 4; ++m)
#pragma unroll
    for (int n = 0; n < 4; ++n) acc[m][n] = zero;

  // ---- staging map: 1024 threads cover the 16KB A region (1024 x 16B
  // chunks) in ONE gld16, ditto B. fat row F = t>>3 (128 per region, 2 tile
  // rows each), slot s = t&7; global logical chunk c = s ^ (F&7);
  // c -> (row parity c>>2, k-chunk c&3)   [rule 21: inverse swizzle on the
  // SOURCE, linear LDS dest].
  const int F = t >> 3;
  const int cc = (t & 7) ^ (F & 7);
  const int strow = 2 * F + (cc >> 2);
  const int stk = (cc & 3) * 8;
  const u16* pA = A + (size_t)(row0 + strow) * K + stk;
  const u16* pB = Bm + (size_t)(col0 + strow) * K + stk;

  auto STAGE = [&](int buf, int kt){
    u16* dst = lds + buf * 16384 + (w << 9);       // wave-uniform base (1KB/wave)
    gld16(dst,        pA + kt);                    // A rows 0..255
    gld16(dst + 8192, pB + kt);                    // B rows 0..255
  };

  // ---- read map (swizzled): fat row R = tilerow>>1, chunk
  // c1 = ((row&1)*4 + g) ^ (R&7); u16 offset = R*64 + c1*8.
  const int c1 = (((r16 & 1) << 2) | g) ^ ((r16 >> 1) & 7);
  const int aoff = (wm * 32 + (r16 >> 1)) * 64 + c1 * 8;
  const int boff = 8192 + (wn * 32 + (r16 >> 1)) * 64 + c1 * 8;

  auto TILECOMP = [&](int buf){
    const u16* base = lds + buf * 16384;
    bf16x8 af[4], bfr[4];
#pragma unroll
    for (int m = 0; m < 4; ++m) af[m] = *(const bf16x8*)(base + aoff + m * 512);
#pragma unroll
    for (int n = 0; n < 4; ++n) bfr[n] = *(const bf16x8*)(base + boff + n * 512);
    __builtin_amdgcn_s_setprio(1);
#pragma unroll
    for (int m = 0; m < 4; ++m)
#pragma unroll
      for (int n = 0; n < 4; ++n)
        acc[m][n] = mfma16(af[m], bfr[n], acc[m][n]);
    __builtin_amdgcn_s_setprio(0);
  };

  // ---- lead-1 double-buffered main loop
  STAGE(0, 0);
  int cb = 0;
  for (int tt = 0; tt < NT - 1; ++tt){
    STAGE(cb ^ 1, (tt + 1) * 32);                  // stage next tile
    asm volatile("s_waitcnt vmcnt(2)" ::: "memory"); // tile tt landed
    __builtin_amdgcn_s_barrier();
    asm volatile("" ::: "memory");
    TILECOMP(cb);
    __builtin_amdgcn_s_barrier();                  // readers done before restage
    asm volatile("" ::: "memory");
    cb ^= 1;
  }
  asm volatile("s_waitcnt vmcnt(0)" ::: "memory"); // last tile landed
  __builtin_amdgcn_s_barrier();
  asm volatile("" ::: "memory");
  TILECOMP(cb);

  // ---- epilogue ----
  float bv[4];
#pragma unroll
  for (int nb = 0; nb < 4; ++nb) bv[nb] = bias[col0 + wn * 64 + nb * 16 + r16];

  if (MODE == 1){
#pragma unroll
    for (int m = 0; m < 4; ++m){
      int row = row0 + wm * 64 + m * 16 + g * 4;
#pragma unroll
      for (int nb = 0; nb < 4; ++nb){
        int n = col0 + wn * 64 + nb * 16 + r16;
#pragma unroll
        for (int j = 0; j < 4; ++j)
          Cf[(size_t)(row + j) * 1024 + n] = acc[m][nb][j] + bv[nb];
      }
    }
  } else {
    const int regn = col0 >> 10;   // uniform per block: 0=Q 1=K 2=V
    if (regn == 0){
#pragma unroll
      for (int m = 0; m < 4; ++m){
        int row = row0 + wm * 64 + m * 16 + g * 4;
#pragma unroll
        for (int nb = 0; nb < 4; ++nb){
          int n = col0 + wn * 64 + nb * 16 + r16;
#pragma unroll
          for (int j = 0; j < 4; ++j)
            Qws[(size_t)(row + j) * 1024 + n] = f2bf(acc[m][nb][j] + bv[nb]);
        }
      }
    } else if (regn == 1){
#pragma unroll
      for (int m = 0; m < 4; ++m){
        int row = row0 + wm * 64 + m * 16 + g * 4;
#pragma unroll
        for (int nb = 0; nb < 4; ++nb){
          int n = col0 + wn * 64 + nb * 16 + r16 - 1024;
#pragma unroll
          for (int j = 0; j < 4; ++j)
            Kws[(size_t)(row + j) * 1024 + n] = f2bf(acc[m][nb][j] + bv[nb]);
        }
      }
    } else {
      // V: store transposed per window: Vt[win][d][rr], win=((b*16+h)*16+wd)
#pragma unroll
      for (int m = 0; m < 4; ++m){
        int row = row0 + wm * 64 + m * 16 + g * 4;
        int bb = row >> 12, s = row & 4095;
        int wdw = s >> 8, rr = s & 255;      // rr multiple of 4
#pragma unroll
        for (int nb = 0; nb < 4; ++nb){
          int n2 = col0 + wn * 64 + nb * 16 + r16 - 2048;
          int hh = n2 >> 6, d = n2 & 63;
          int winw = (bb * 16 + hh) * 16 + wdw;
          u16x4 pk;
#pragma unroll
          for (int j = 0; j < 4; ++j) pk[j] = f2bf(acc[m][nb][j] + bv[nb]);
          *(u16x4*)(Vtws + (size_t)winw * 16384 + d * 256 + rr) = pk;
        }
      }
    }
  }
}

// ---------------- windowed attention (resident K/V, barrier-free loop) ----
// (unchanged — 1 block/window, all K/V in LDS, one barrier, no
// max-subtraction, MFMA row-sums.)
__global__ __launch_bounds__(256, 1)
void attn_win(const u16* __restrict__ Q, const u16* __restrict__ Kws,
              const u16* __restrict__ Vt, u16* __restrict__ Oo)
{
  __shared__ __align__(16) u16 Kl[16384];   // 32 KB: 4 x [64 r x 64 d]
  __shared__ __align__(16) u16 Vl[16384];   // 32 KB: [64 d][256 k]
  __shared__ __align__(16) u16 Pl[16384];   // 32 KB: 4 waves x [64 q x 64 k]
  const int t = threadIdx.x;
  const int wv = t >> 6, l = t & 63, g = l >> 4, r16 = l & 15;
  const int win = blockIdx.x;
  const int b = win >> 8, h = (win >> 4) & 15, wd = win & 15;
  const int s0 = b * 4096 + wd * 256;
  const size_t vwin = (size_t)win * 16384;

  {
    const int rloc = l >> 3, sl = l & 7;
    const u16* ksrc = Kws + (size_t)(s0 + wv * 64 + rloc) * 1024 + h * 64
                      + ((sl ^ rloc) << 3);
#pragma unroll
    for (int j = 0; j < 8; ++j)
      gld16(Kl + wv * 4096 + j * 512, ksrc + (size_t)j * 8 * 1024);
    const int dloc = l >> 5, kcv = (l >> 3) & 3, slv = l & 7;
#pragma unroll
    for (int j = 0; j < 8; ++j){
      int d = wv * 16 + j * 2 + dloc;
      gld16(Vl + (wv * 8 + j) * 512,
            Vt + vwin + (size_t)d * 256 + kcv * 64 + ((slv ^ (d & 7)) << 3));
    }
  }

  bf16x8 aq[4][2];
#pragma unroll
  for (int qm = 0; qm < 4; ++qm)
#pragma unroll
    for (int kk = 0; kk < 2; ++kk)
      aq[qm][kk] = *(const bf16x8*)(Q + (size_t)(s0 + wv * 64 + qm * 16 + r16) * 1024
                                      + h * 64 + kk * 32 + g * 8);

  const f32x4 zero = {0.f, 0.f, 0.f, 0.f};
  f32x4 o[4][4];
  f32x4 lsum[4];
#pragma unroll
  for (int qm = 0; qm < 4; ++qm){
    lsum[qm] = zero;
#pragma unroll
    for (int nd = 0; nd < 4; ++nd) o[qm][nd] = zero;
  }
  bf16x8 onesb;
#pragma unroll
  for (int e = 0; e < 8; ++e) onesb[e] = (__bf16)1.0f;

  const float cl2 = 0.125f * 1.44269504f;

  __syncthreads();

  for (int kc = 0; kc < 4; ++kc){
    f32x4 sc[4][4];
#pragma unroll
    for (int qm = 0; qm < 4; ++qm)
#pragma unroll
      for (int nb = 0; nb < 4; ++nb) sc[qm][nb] = zero;
#pragma unroll
    for (int kk = 0; kk < 2; ++kk){
      bf16x8 kb[4];
#pragma unroll
      for (int nb = 0; nb < 4; ++nb)
        kb[nb] = *(const bf16x8*)(Kl + kc * 4096 + (nb * 16 + r16) * 64
                                  + ((((kk << 2) | g) ^ (r16 & 7)) << 3));
#pragma unroll
      for (int qm = 0; qm < 4; ++qm)
#pragma unroll
        for (int nb = 0; nb < 4; ++nb)
          sc[qm][nb] = mfma16(aq[qm][kk], kb[nb], sc[qm][nb]);
    }

#pragma unroll
    for (int qm = 0; qm < 4; ++qm){
#pragma unroll
      for (int j = 0; j < 4; ++j){
        int q = qm * 16 + g * 4 + j;
        u16* pbase = Pl + wv * 4096 + q * 64;
#pragma unroll
        for (int nb = 0; nb < 4; ++nb){
          float p = __builtin_amdgcn_exp2f(sc[qm][nb][j] * cl2);
          int k = nb * 16 + r16;
          pbase[(k & 7) + (((k >> 3) ^ (q & 7)) << 3)] = f2bf(p);
        }
      }
    }

#pragma unroll
    for (int kc32 = 0; kc32 < 2; ++kc32){
      bf16x8 pa[4], vb[4];
#pragma unroll
      for (int qm = 0; qm < 4; ++qm)
        pa[qm] = *(const bf16x8*)(Pl + wv * 4096 + (qm * 16 + r16) * 64
                                  + ((((kc32 << 2) | g) ^ (r16 & 7)) << 3));
#pragma unroll
      for (int nd = 0; nd < 4; ++nd){
        int d = nd * 16 + r16;
        vb[nd] = *(const bf16x8*)(Vl + d * 256 + kc * 64
                                  + ((((kc32 << 2) | g) ^ (r16 & 7)) << 3));
      }
#pragma unroll
      for (int qm = 0; qm < 4; ++qm){
        lsum[qm] = mfma16(pa[qm], onesb, lsum[qm]);
#pragma unroll
        for (int nd = 0; nd < 4; ++nd)
          o[qm][nd] = mfma16(pa[qm], vb[nd], o[qm][nd]);
      }
    }
  }

#pragma unroll
  for (int qm = 0; qm < 4; ++qm){
#pragma unroll
    for (int j = 0; j < 4; ++j){
      float inv = 1.f / lsum[qm][j];
      int row = s0 + wv * 64 + qm * 16 + g * 4 + j;
#pragma unroll
      for (int nd = 0; nd < 4; ++nd)
        Oo[(size_t)row * 1024 + h * 64 + nd * 16 + r16] = f2bf(o[qm][nd][j] * inv);
    }
  }
}

// ---------------- launch ----------------
extern "C" void kernel_launch(void* const* d_in, const int* in_sizes, int n_in,
                              void* d_out, int out_size, void* d_ws, size_t ws_size,
                              hipStream_t stream)
{
  (void)in_sizes; (void)n_in; (void)out_size; (void)ws_size;
  const float* x  = (const float*)d_in[0];
  const float* Wq = (const float*)d_in[1];
  const float* bq = (const float*)d_in[2];
  const float* Wo = (const float*)d_in[3];
  const float* bo = (const float*)d_in[4];

  char* ws = (char*)d_ws;
  const size_t SZ = (size_t)16384 * 1024 * 2;          // 33.5 MB
  u16* xb  = (u16*)(ws);                               // x bf16, later reused for attn out
  u16* Vt  = (u16*)(ws + SZ);                          // V transposed per window
  u16* wqb = (u16*)(ws + 2 * SZ);                      // W_qkv bf16 (6.29 MB)
  u16* wob = (u16*)(ws + 2 * SZ + 6291456);            // W_out bf16 (2.1 MB)
  u16* Qws = (u16*)d_out;
  u16* Kws = (u16*)d_out + (size_t)16384 * 1024;

  cvt_bf16<<<2048, 256, 0, stream>>>(x,  xb,  16777216 / 4);
  cvt_bf16<<<768,  256, 0, stream>>>(Wq, wqb, 3145728 / 4);
  cvt_bf16<<<256,  256, 0, stream>>>(Wo, wob, 1048576 / 4);

  gemm_bt<0><<<dim3(12, 64), 1024, 0, stream>>>(xb, wqb, bq, Qws, Kws, Vt, nullptr);

  attn_win<<<1024, 256, 0, stream>>>(Qws, Kws, Vt, xb);

  gemm_bt<1><<<dim3(4, 64), 1024, 0, stream>>>(xb, wob, bo,
                                               nullptr, nullptr, nullptr,
                                               (float*)d_out);
}

// Round 11
// 230.734 us; speedup vs baseline: 8.2713x; 8.2713x over previous
//
#include <hip/hip_runtime.h>

typedef unsigned short u16;
typedef __bf16 bf16x8 __attribute__((ext_vector_type(8)));
typedef float f32x4 __attribute__((ext_vector_type(4)));
typedef u16 u16x4 __attribute__((ext_vector_type(4)));

#define DEVI static __device__ __forceinline__

DEVI u16 f2bf(float f){
  unsigned u = __float_as_uint(f);
  u += 0x7FFFu + ((u >> 16) & 1u);
  return (u16)(u >> 16);
}

DEVI f32x4 mfma16(bf16x8 a, bf16x8 b, f32x4 c){
  return __builtin_amdgcn_mfma_f32_16x16x32_bf16(a, b, c, 0, 0, 0);
}

DEVI void gld16(u16* lds, const u16* g){
  __builtin_amdgcn_global_load_lds(
      (const __attribute__((address_space(1))) void*)g,
      (__attribute__((address_space(3))) void*)lds, 16, 0, 0);
}

// ---------------- fp32 -> bf16 convert ----------------
__global__ void cvt_bf16(const float* __restrict__ s, u16* __restrict__ d, int n4){
  int i = blockIdx.x * blockDim.x + threadIdx.x;
  int stride = gridDim.x * blockDim.x;
  for (; i < n4; i += stride){
    float4 v = *(const float4*)(s + (size_t)i * 4);
    u16x4 o = { f2bf(v.x), f2bf(v.y), f2bf(v.z), f2bf(v.w) };
    *(u16x4*)(d + (size_t)i * 4) = o;
  }
}

// ---------------- GEMM: C = A * Bm^T + bias (m201 8-phase port) ----------
// 256x256 tile, BK=64, 512 threads (8 waves 2Mx4N, per-wave 128x64 out,
// acc = 128 regs; __launch_bounds__(512,2) -> VGPR cap 256, 2 waves/SIMD).
// TWO 64KB LDS buffers (128 KiB, 1 block/CU). 4 phases per K-tile:
//   ph0: ds_read all-B(8) + A m0,m1(4) || stage Ah0(t+1)->buf^1 ; bar;
//        lgkmcnt(0); setprio(1) 16 MFMA setprio(0); bar
//   ph1: A m2,m3 || stage Ah1(t+1)   ph2: A m4,m5 || stage Bh0(t+2)->buf
//   ph3: A m6,m7 || stage Bh1(t+2); ...; vmcnt(4); bar
// Region-deadness staging: B(buf) dead after ph0's closing barrier, A(buf)
// after ph3's -> A(t+1) goes to the OTHER buffer at ph0/ph1, B(t+2) to the
// CURRENT buffer at ph2/ph3. Counted vmcnt(4)/tile (tile t+1's 4 trailing
// loads in flight), never 0 mid-loop. Fat-row swizzle (rows are 128B at
// BK=64): 16B chunk ^= row&7, linear gld_lds dest + inverse-swizzled
// global source + swizzled ds_read (conflicts = 0).
// MODE 0: QKV epilogue; MODE 1: fp32 + bias.
template<int MODE>
__global__ __launch_bounds__(512, 2)
void gemm_bt(const u16* __restrict__ A, const u16* __restrict__ Bm,
             const float* __restrict__ bias,
             u16* __restrict__ Qws, u16* __restrict__ Kws, u16* __restrict__ Vtws,
             float* __restrict__ Cf)
{
  constexpr int K = 1024;
  constexpr int NT = K / 64;                       // 16 K-tiles
  __shared__ __align__(16) u16 lds[2 * 32768];     // 128 KiB
  const int t = threadIdx.x;
  const int w = t >> 6, l = t & 63, g = l >> 4, r16 = l & 15;
  const int wm = w >> 2, wn = w & 3;               // 2Mx4N wave grid

  // XCD-bijective block swizzle (nwg % 8 == 0 in both modes)
  constexpr int NBX = (MODE == 0) ? 12 : 4;
  constexpr int NWG = NBX * 64;
  const int orig = blockIdx.y * NBX + blockIdx.x;
  const int swzb = (orig & 7) * (NWG >> 3) + (orig >> 3);
  const int row0 = (swzb / NBX) * 256, col0 = (swzb % NBX) * 256;

  const f32x4 zero = {0.f, 0.f, 0.f, 0.f};
  f32x4 acc[8][4];
#pragma unroll
  for (int m = 0; m < 8; ++m)
#pragma unroll
    for (int n = 0; n < 4; ++n) acc[m][n] = zero;

  // ---- staging map: per half (128 rows x 64 u16 = 16KB) a wave-pair of
  // glds: gld i covers rows i*64 + (t>>3). LDS chunk t linear; global
  // chunk = (t&7) ^ ((t>>3)&7)   [rule 21 inverse-swizzle on source].
  const int trow = t >> 3;
  const int tcol = (t & 7) ^ (trow & 7);
  const u16* pA = A + (size_t)(row0 + trow) * K + tcol * 8;
  const u16* pB = Bm + (size_t)(col0 + trow) * K + tcol * 8;

  // ---- read maps (swizzled): row stride 64 u16 (128B); chunk-in-row for
  // k-slice ks, group g: ((ks*4+g) ^ (r16&7)).
  const int sk0 = ((g) ^ (r16 & 7)) << 3;
  const int sk1 = ((4 | g) ^ (r16 & 7)) << 3;
  const int aoffb = (wm * 128 + r16) * 64;
  const int boffb = 16384 + (wn * 64 + r16) * 64;

  bf16x8 bfr[4][2];

  // one phase: reads A m=2mq,2mq+1 (+ all B if mq==0), optional 1-half
  // stage, then bar/lgkm/MFMA/bar (+ optional end-of-tile vmcnt).
  auto PHASE = [&](const u16* base, int mq, u16* sdst, const u16* ssrc,
                   int endvm){
    bf16x8 a0[2], a1[2];
    if (mq == 0){
#pragma unroll
      for (int n = 0; n < 4; ++n){
        bfr[n][0] = *(const bf16x8*)(base + boffb + n * 1024 + sk0);
        bfr[n][1] = *(const bf16x8*)(base + boffb + n * 1024 + sk1);
      }
    }
    a0[0] = *(const bf16x8*)(base + aoffb + (2 * mq) * 1024 + sk0);
    a0[1] = *(const bf16x8*)(base + aoffb + (2 * mq) * 1024 + sk1);
    a1[0] = *(const bf16x8*)(base + aoffb + (2 * mq + 1) * 1024 + sk0);
    a1[1] = *(const bf16x8*)(base + aoffb + (2 * mq + 1) * 1024 + sk1);
    if (sdst){
      gld16(sdst,        ssrc);
      gld16(sdst + 4096, ssrc + (size_t)64 * K);
    }
    __builtin_amdgcn_s_barrier();
    asm volatile("s_waitcnt lgkmcnt(0)" ::: "memory");
    __builtin_amdgcn_sched_barrier(0);
    __builtin_amdgcn_s_setprio(1);
#pragma unroll
    for (int n = 0; n < 4; ++n){
      acc[2 * mq][n]     = mfma16(a0[0], bfr[n][0], acc[2 * mq][n]);
      acc[2 * mq][n]     = mfma16(a0[1], bfr[n][1], acc[2 * mq][n]);
      acc[2 * mq + 1][n] = mfma16(a1[0], bfr[n][0], acc[2 * mq + 1][n]);
      acc[2 * mq + 1][n] = mfma16(a1[1], bfr[n][1], acc[2 * mq + 1][n]);
    }
    __builtin_amdgcn_s_setprio(0);
    if (endvm == 4)      asm volatile("s_waitcnt vmcnt(4)" ::: "memory");
    else if (endvm == 0) asm volatile("s_waitcnt vmcnt(0)" ::: "memory");
    __builtin_amdgcn_s_barrier();
    asm volatile("" ::: "memory");
  };

  // TILE: compute tile in buf p; stage A(kA)->buf p^1 (ph0/ph1),
  // B(kB)->buf p (ph2/ph3); end-of-tile vmcnt = endvm.
  auto TILE = [&](int p, int kA, int kB, int endvm){
    const u16* base = lds + p * 32768;
    u16* aw = lds + (p ^ 1) * 32768 + (w << 9);
    u16* bw = lds + p * 32768 + 16384 + (w << 9);
    PHASE(base, 0, kA >= 0 ? aw        : nullptr, pA + kA, -1);
    PHASE(base, 1, kA >= 0 ? aw + 8192 : nullptr, pA + (size_t)128 * K + kA, -1);
    PHASE(base, 2, kB >= 0 ? bw        : nullptr, pB + kB, -1);
    PHASE(base, 3, kB >= 0 ? bw + 8192 : nullptr, pB + (size_t)128 * K + kB, endvm);
  };

  // ---- prologue: tile0 all 4 halves -> buf0; tile1 B halves -> buf1
  {
    u16* d0 = lds + (w << 9);
    gld16(d0,                 pA);
    gld16(d0 + 4096,          pA + (size_t)64 * K);
    gld16(d0 + 8192,          pA + (size_t)128 * K);
    gld16(d0 + 12288,         pA + (size_t)192 * K);
    gld16(d0 + 16384,         pB);
    gld16(d0 + 16384 + 4096,  pB + (size_t)64 * K);
    gld16(d0 + 16384 + 8192,  pB + (size_t)128 * K);
    gld16(d0 + 16384 + 12288, pB + (size_t)192 * K);
    u16* d1 = lds + 32768 + 16384 + (w << 9);
    gld16(d1,         pB + 64);
    gld16(d1 + 4096,  pB + (size_t)64 * K + 64);
    gld16(d1 + 8192,  pB + (size_t)128 * K + 64);
    gld16(d1 + 12288, pB + (size_t)192 * K + 64);
  }
  asm volatile("s_waitcnt vmcnt(4)" ::: "memory");   // tile 0 landed
  __builtin_amdgcn_s_barrier();
  asm volatile("" ::: "memory");

  for (int tt = 0; tt < NT - 2; ++tt)                // tiles 0..13
    TILE(tt & 1, (tt + 1) * 64, (tt + 2) * 64, 4);
  TILE(0, (NT - 1) * 64, -1, 0);                     // tile 14: stage A(15) only
  TILE(1, -1, -1, -1);                               // tile 15: tail

  // ---- epilogue ----
  float bv[4];
#pragma unroll
  for (int nb = 0; nb < 4; ++nb) bv[nb] = bias[col0 + wn * 64 + nb * 16 + r16];

  if (MODE == 1){
#pragma unroll
    for (int m = 0; m < 8; ++m){
      int row = row0 + wm * 128 + m * 16 + g * 4;
#pragma unroll
      for (int nb = 0; nb < 4; ++nb){
        int n = col0 + wn * 64 + nb * 16 + r16;
#pragma unroll
        for (int j = 0; j < 4; ++j)
          Cf[(size_t)(row + j) * 1024 + n] = acc[m][nb][j] + bv[nb];
      }
    }
  } else {
    const int regn = col0 >> 10;   // uniform per block: 0=Q 1=K 2=V
    if (regn == 0){
#pragma unroll
      for (int m = 0; m < 8; ++m){
        int row = row0 + wm * 128 + m * 16 + g * 4;
#pragma unroll
        for (int nb = 0; nb < 4; ++nb){
          int n = col0 + wn * 64 + nb * 16 + r16;
#pragma unroll
          for (int j = 0; j < 4; ++j)
            Qws[(size_t)(row + j) * 1024 + n] = f2bf(acc[m][nb][j] + bv[nb]);
        }
      }
    } else if (regn == 1){
#pragma unroll
      for (int m = 0; m < 8; ++m){
        int row = row0 + wm * 128 + m * 16 + g * 4;
#pragma unroll
        for (int nb = 0; nb < 4; ++nb){
          int n = col0 + wn * 64 + nb * 16 + r16 - 1024;
#pragma unroll
          for (int j = 0; j < 4; ++j)
            Kws[(size_t)(row + j) * 1024 + n] = f2bf(acc[m][nb][j] + bv[nb]);
        }
      }
    } else {
      // V: store transposed per window: Vt[win][d][rr], win=((b*16+h)*16+wd)
#pragma unroll
      for (int m = 0; m < 8; ++m){
        int row = row0 + wm * 128 + m * 16 + g * 4;
        int bb = row >> 12, s = row & 4095;
        int wdw = s >> 8, rr = s & 255;      // rr multiple of 4
#pragma unroll
        for (int nb = 0; nb < 4; ++nb){
          int n2 = col0 + wn * 64 + nb * 16 + r16 - 2048;
          int hh = n2 >> 6, d = n2 & 63;
          int winw = (bb * 16 + hh) * 16 + wdw;
          u16x4 pk;
#pragma unroll
          for (int j = 0; j < 4; ++j) pk[j] = f2bf(acc[m][nb][j] + bv[nb]);
          *(u16x4*)(Vtws + (size_t)winw * 16384 + d * 256 + rr) = pk;
        }
      }
    }
  }
}

// ---------------- windowed attention (resident K/V, barrier-free loop) ----
// (unchanged from R9 — 1 block/window, all K/V in LDS, one barrier, no
// max-subtraction, MFMA row-sums.)
__global__ __launch_bounds__(256, 1)
void attn_win(const u16* __restrict__ Q, const u16* __restrict__ Kws,
              const u16* __restrict__ Vt, u16* __restrict__ Oo)
{
  __shared__ __align__(16) u16 Kl[16384];   // 32 KB: 4 x [64 r x 64 d]
  __shared__ __align__(16) u16 Vl[16384];   // 32 KB: [64 d][256 k]
  __shared__ __align__(16) u16 Pl[16384];   // 32 KB: 4 waves x [64 q x 64 k]
  const int t = threadIdx.x;
  const int wv = t >> 6, l = t & 63, g = l >> 4, r16 = l & 15;
  const int win = blockIdx.x;
  const int b = win >> 8, h = (win >> 4) & 15, wd = win & 15;
  const int s0 = b * 4096 + wd * 256;
  const size_t vwin = (size_t)win * 16384;

  {
    const int rloc = l >> 3, sl = l & 7;
    const u16* ksrc = Kws + (size_t)(s0 + wv * 64 + rloc) * 1024 + h * 64
                      + ((sl ^ rloc) << 3);
#pragma unroll
    for (int j = 0; j < 8; ++j)
      gld16(Kl + wv * 4096 + j * 512, ksrc + (size_t)j * 8 * 1024);
    const int dloc = l >> 5, kcv = (l >> 3) & 3, slv = l & 7;
#pragma unroll
    for (int j = 0; j < 8; ++j){
      int d = wv * 16 + j * 2 + dloc;
      gld16(Vl + (wv * 8 + j) * 512,
            Vt + vwin + (size_t)d * 256 + kcv * 64 + ((slv ^ (d & 7)) << 3));
    }
  }

  bf16x8 aq[4][2];
#pragma unroll
  for (int qm = 0; qm < 4; ++qm)
#pragma unroll
    for (int kk = 0; kk < 2; ++kk)
      aq[qm][kk] = *(const bf16x8*)(Q + (size_t)(s0 + wv * 64 + qm * 16 + r16) * 1024
                                      + h * 64 + kk * 32 + g * 8);

  const f32x4 zero = {0.f, 0.f, 0.f, 0.f};
  f32x4 o[4][4];
  f32x4 lsum[4];
#pragma unroll
  for (int qm = 0; qm < 4; ++qm){
    lsum[qm] = zero;
#pragma unroll
    for (int nd = 0; nd < 4; ++nd) o[qm][nd] = zero;
  }
  bf16x8 onesb;
#pragma unroll
  for (int e = 0; e < 8; ++e) onesb[e] = (__bf16)1.0f;

  const float cl2 = 0.125f * 1.44269504f;

  __syncthreads();

  for (int kc = 0; kc < 4; ++kc){
    f32x4 sc[4][4];
#pragma unroll
    for (int qm = 0; qm < 4; ++qm)
#pragma unroll
      for (int nb = 0; nb < 4; ++nb) sc[qm][nb] = zero;
#pragma unroll
    for (int kk = 0; kk < 2; ++kk){
      bf16x8 kb[4];
#pragma unroll
      for (int nb = 0; nb < 4; ++nb)
        kb[nb] = *(const bf16x8*)(Kl + kc * 4096 + (nb * 16 + r16) * 64
                                  + ((((kk << 2) | g) ^ (r16 & 7)) << 3));
#pragma unroll
      for (int qm = 0; qm < 4; ++qm)
#pragma unroll
        for (int nb = 0; nb < 4; ++nb)
          sc[qm][nb] = mfma16(aq[qm][kk], kb[nb], sc[qm][nb]);
    }

#pragma unroll
    for (int qm = 0; qm < 4; ++qm){
#pragma unroll
      for (int j = 0; j < 4; ++j){
        int q = qm * 16 + g * 4 + j;
        u16* pbase = Pl + wv * 4096 + q * 64;
#pragma unroll
        for (int nb = 0; nb < 4; ++nb){
          float p = __builtin_amdgcn_exp2f(sc[qm][nb][j] * cl2);
          int k = nb * 16 + r16;
          pbase[(k & 7) + (((k >> 3) ^ (q & 7)) << 3)] = f2bf(p);
        }
      }
    }

#pragma unroll
    for (int kc32 = 0; kc32 < 2; ++kc32){
      bf16x8 pa[4], vb[4];
#pragma unroll
      for (int qm = 0; qm < 4; ++qm)
        pa[qm] = *(const bf16x8*)(Pl + wv * 4096 + (qm * 16 + r16) * 64
                                  + ((((kc32 << 2) | g) ^ (r16 & 7)) << 3));
#pragma unroll
      for (int nd = 0; nd < 4; ++nd){
        int d = nd * 16 + r16;
        vb[nd] = *(const bf16x8*)(Vl + d * 256 + kc * 64
                                  + ((((kc32 << 2) | g) ^ (r16 & 7)) << 3));
      }
#pragma unroll
      for (int qm = 0; qm < 4; ++qm){
        lsum[qm] = mfma16(pa[qm], onesb, lsum[qm]);
#pragma unroll
        for (int nd = 0; nd < 4; ++nd)
          o[qm][nd] = mfma16(pa[qm], vb[nd], o[qm][nd]);
      }
    }
  }

#pragma unroll
  for (int qm = 0; qm < 4; ++qm){
#pragma unroll
    for (int j = 0; j < 4; ++j){
      float inv = 1.f / lsum[qm][j];
      int row = s0 + wv * 64 + qm * 16 + g * 4 + j;
#pragma unroll
      for (int nd = 0; nd < 4; ++nd)
        Oo[(size_t)row * 1024 + h * 64 + nd * 16 + r16] = f2bf(o[qm][nd][j] * inv);
    }
  }
}

// ---------------- launch ----------------
extern "C" void kernel_launch(void* const* d_in, const int* in_sizes, int n_in,
                              void* d_out, int out_size, void* d_ws, size_t ws_size,
                              hipStream_t stream)
{
  (void)in_sizes; (void)n_in; (void)out_size; (void)ws_size;
  const float* x  = (const float*)d_in[0];
  const float* Wq = (const float*)d_in[1];
  const float* bq = (const float*)d_in[2];
  const float* Wo = (const float*)d_in[3];
  const float* bo = (const float*)d_in[4];

  char* ws = (char*)d_ws;
  const size_t SZ = (size_t)16384 * 1024 * 2;          // 33.5 MB
  u16* xb  = (u16*)(ws);                               // x bf16, later reused for attn out
  u16* Vt  = (u16*)(ws + SZ);                          // V transposed per window
  u16* wqb = (u16*)(ws + 2 * SZ);                      // W_qkv bf16 (6.29 MB)
  u16* wob = (u16*)(ws + 2 * SZ + 6291456);            // W_out bf16 (2.1 MB)
  u16* Qws = (u16*)d_out;
  u16* Kws = (u16*)d_out + (size_t)16384 * 1024;

  cvt_bf16<<<2048, 256, 0, stream>>>(x,  xb,  16777216 / 4);
  cvt_bf16<<<768,  256, 0, stream>>>(Wq, wqb, 3145728 / 4);
  cvt_bf16<<<256,  256, 0, stream>>>(Wo, wob, 1048576 / 4);

  gemm_bt<0><<<dim3(12, 64), 512, 0, stream>>>(xb, wqb, bq, Qws, Kws, Vt, nullptr);

  attn_win<<<1024, 256, 0, stream>>>(Qws, Kws, Vt, xb);

  gemm_bt<1><<<dim3(4, 64), 512, 0, stream>>>(xb, wob, bo,
                                              nullptr, nullptr, nullptr,
                                              (float*)d_out);
}

// Round 12
// 227.081 us; speedup vs baseline: 8.4044x; 1.0161x over previous
//
#include <hip/hip_runtime.h>

typedef unsigned short u16;
typedef __bf16 bf16x8 __attribute__((ext_vector_type(8)));
typedef float f32x4 __attribute__((ext_vector_type(4)));
typedef u16 u16x4 __attribute__((ext_vector_type(4)));

#define DEVI static __device__ __forceinline__

DEVI u16 f2bf(float f){
  unsigned u = __float_as_uint(f);
  u += 0x7FFFu + ((u >> 16) & 1u);
  return (u16)(u >> 16);
}

DEVI f32x4 mfma16(bf16x8 a, bf16x8 b, f32x4 c){
  return __builtin_amdgcn_mfma_f32_16x16x32_bf16(a, b, c, 0, 0, 0);
}

DEVI void gld16(u16* lds, const u16* g){
  __builtin_amdgcn_global_load_lds(
      (const __attribute__((address_space(1))) void*)g,
      (__attribute__((address_space(3))) void*)lds, 16, 0, 0);
}

// ---------------- fp32 -> bf16 convert (all three tensors, one launch) ----
__global__ void cvt_all(const float* __restrict__ x,  u16* __restrict__ xd,
                        const float* __restrict__ wq, u16* __restrict__ wqd,
                        const float* __restrict__ wo, u16* __restrict__ wod){
  constexpr int NX = 4194304;            // 16777216/4
  constexpr int NQ = 786432;             // 3145728/4
  constexpr int NO = 262144;             // 1048576/4
  int i = blockIdx.x * blockDim.x + threadIdx.x;
  int stride = gridDim.x * blockDim.x;
  for (; i < NX + NQ + NO; i += stride){
    const float* s; u16* d; int j;
    if (i < NX){ s = x; d = xd; j = i; }
    else if (i < NX + NQ){ s = wq; d = wqd; j = i - NX; }
    else { s = wo; d = wod; j = i - NX - NQ; }
    float4 v = *(const float4*)(s + (size_t)j * 4);
    u16x4 o = { f2bf(v.x), f2bf(v.y), f2bf(v.z), f2bf(v.w) };
    *(u16x4*)(d + (size_t)j * 4) = o;
  }
}

// ---------------- GEMM: C = A * Bm^T + bias ----------------
// 128x256 tile (MxN), BK=32, 512 threads (8 waves 2Mx4N, each 64x64 out,
// acc 64 AGPR + ~60 VGPR ~ 124 total). __launch_bounds__(512,4) caps the
// unified file at 128 -> TWO blocks/CU (LDS 2x48KB=96KB): independent
// barrier groups overlap MFMA with the sibling's barrier/drain stalls
// (m114 — the piece R9's 1-block/CU config lacked). N stays 256 so x is
// read only 12x (R8's FETCH blowup was N=128); extra M-round weight reuse
// is L3-resident (6.3 MB).
// TWO 24KB LDS buffers, lead-1 double-buffer, counted vmcnt(3) (3 loads/
// tile in flight for tile t+1; never 0 mid-loop), 2 barriers/tile.
// Fat-row swizzle (128B fat rows = 2 tile rows, 16B chunk ^= fatrow&7):
// linear gld_lds dest + inverse-swizzled global source + swizzled ds_read
// (conflicts = 0). MODE 0: QKV epilogue; MODE 1: fp32 + bias.
template<int MODE>
__global__ __launch_bounds__(512, 4)
void gemm_bt(const u16* __restrict__ A, const u16* __restrict__ Bm,
             const float* __restrict__ bias,
             u16* __restrict__ Qws, u16* __restrict__ Kws, u16* __restrict__ Vtws,
             float* __restrict__ Cf)
{
  constexpr int K = 1024;
  constexpr int NT = K / 32;                       // 32 K-tiles
  __shared__ __align__(16) u16 lds[2 * 12288];     // 48 KiB (A 8KB + B 16KB per buf)
  const int t = threadIdx.x;
  const int w = t >> 6, l = t & 63, g = l >> 4, r16 = l & 15;
  const int wm = w >> 2, wn = w & 3;               // 2Mx4N wave grid

  // XCD-bijective block swizzle (nwg % 8 == 0 in both modes)
  constexpr int NBX = (MODE == 0) ? 12 : 4;
  constexpr int NWG = NBX * 128;
  const int orig = blockIdx.y * NBX + blockIdx.x;
  const int swzb = (orig & 7) * (NWG >> 3) + (orig >> 3);
  const int row0 = (swzb / NBX) * 128, col0 = (swzb % NBX) * 256;

  const f32x4 zero = {0.f, 0.f, 0.f, 0.f};
  f32x4 acc[4][4];
#pragma unroll
  for (int m = 0; m < 4; ++m)
#pragma unroll
    for (int n = 0; n < 4; ++n) acc[m][n] = zero;

  // ---- staging map: 512 threads x 16B = 8KB per gld16 issue.
  // A tile (128 rows x 64B) = 1 issue; B tile (256 rows) = 2 issues.
  // fat row F = t>>3, slot s = t&7; global chunk c = s ^ (F&7);
  // c -> (row parity c>>2, k-chunk c&3)  [rule 21: inverse swizzle on the
  // SOURCE, linear LDS dest].
  const int F = t >> 3;
  const int cc = (t & 7) ^ (F & 7);
  const int strow = 2 * F + (cc >> 2);
  const int stk = (cc & 3) * 8;
  const u16* pA = A + (size_t)(row0 + strow) * K + stk;
  const u16* pB = Bm + (size_t)(col0 + strow) * K + stk;

  auto STAGE = [&](int buf, int kt){
    u16* dst = lds + buf * 12288 + (w << 9);       // wave-uniform base (1KB/wave)
    gld16(dst,        pA + kt);                    // A rows   0..127
    gld16(dst + 4096, pB + kt);                    // B rows   0..127
    gld16(dst + 8192, pB + (size_t)128 * K + kt);  // B rows 128..255
  };

  // ---- read map (swizzled): fat row R = tilerow>>1, chunk
  // c1 = ((row&1)*4 + g) ^ (R&7); u16 offset = R*64 + c1*8.
  const int c1 = (((r16 & 1) << 2) | g) ^ ((r16 >> 1) & 7);
  const int aoff = (wm * 32 + (r16 >> 1)) * 64 + c1 * 8;
  const int boff = 4096 + (wn * 32 + (r16 >> 1)) * 64 + c1 * 8;

  auto TILECOMP = [&](int buf){
    const u16* base = lds + buf * 12288;
    bf16x8 af[4], bfr[4];
#pragma unroll
    for (int m = 0; m < 4; ++m) af[m] = *(const bf16x8*)(base + aoff + m * 512);
#pragma unroll
    for (int n = 0; n < 4; ++n) bfr[n] = *(const bf16x8*)(base + boff + n * 512);
    __builtin_amdgcn_s_setprio(1);
#pragma unroll
    for (int m = 0; m < 4; ++m)
#pragma unroll
      for (int n = 0; n < 4; ++n)
        acc[m][n] = mfma16(af[m], bfr[n], acc[m][n]);
    __builtin_amdgcn_s_setprio(0);
  };

  // ---- lead-1 double-buffered main loop
  STAGE(0, 0);
  int cb = 0;
  for (int tt = 0; tt < NT - 1; ++tt){
    STAGE(cb ^ 1, (tt + 1) * 32);                    // stage next tile
    asm volatile("s_waitcnt vmcnt(3)" ::: "memory"); // tile tt landed
    __builtin_amdgcn_s_barrier();
    asm volatile("" ::: "memory");
    TILECOMP(cb);
    __builtin_amdgcn_s_barrier();                    // readers done before restage
    asm volatile("" ::: "memory");
    cb ^= 1;
  }
  asm volatile("s_waitcnt vmcnt(0)" ::: "memory");   // last tile landed
  __builtin_amdgcn_s_barrier();
  asm volatile("" ::: "memory");
  TILECOMP(cb);

  // ---- epilogue ----
  float bv[4];
#pragma unroll
  for (int nb = 0; nb < 4; ++nb) bv[nb] = bias[col0 + wn * 64 + nb * 16 + r16];

  if (MODE == 1){
#pragma unroll
    for (int m = 0; m < 4; ++m){
      int row = row0 + wm * 64 + m * 16 + g * 4;
#pragma unroll
      for (int nb = 0; nb < 4; ++nb){
        int n = col0 + wn * 64 + nb * 16 + r16;
#pragma unroll
        for (int j = 0; j < 4; ++j)
          Cf[(size_t)(row + j) * 1024 + n] = acc[m][nb][j] + bv[nb];
      }
    }
  } else {
    const int regn = col0 >> 10;   // uniform per block: 0=Q 1=K 2=V
    if (regn == 0){
#pragma unroll
      for (int m = 0; m < 4; ++m){
        int row = row0 + wm * 64 + m * 16 + g * 4;
#pragma unroll
        for (int nb = 0; nb < 4; ++nb){
          int n = col0 + wn * 64 + nb * 16 + r16;
#pragma unroll
          for (int j = 0; j < 4; ++j)
            Qws[(size_t)(row + j) * 1024 + n] = f2bf(acc[m][nb][j] + bv[nb]);
        }
      }
    } else if (regn == 1){
#pragma unroll
      for (int m = 0; m < 4; ++m){
        int row = row0 + wm * 64 + m * 16 + g * 4;
#pragma unroll
        for (int nb = 0; nb < 4; ++nb){
          int n = col0 + wn * 64 + nb * 16 + r16 - 1024;
#pragma unroll
          for (int j = 0; j < 4; ++j)
            Kws[(size_t)(row + j) * 1024 + n] = f2bf(acc[m][nb][j] + bv[nb]);
        }
      }
    } else {
      // V: store transposed per window: Vt[win][d][rr], win=((b*16+h)*16+wd)
#pragma unroll
      for (int m = 0; m < 4; ++m){
        int row = row0 + wm * 64 + m * 16 + g * 4;
        int bb = row >> 12, s = row & 4095;
        int wdw = s >> 8, rr = s & 255;      // rr multiple of 4
#pragma unroll
        for (int nb = 0; nb < 4; ++nb){
          int n2 = col0 + wn * 64 + nb * 16 + r16 - 2048;
          int hh = n2 >> 6, d = n2 & 63;
          int winw = (bb * 16 + hh) * 16 + wdw;
          u16x4 pk;
#pragma unroll
          for (int j = 0; j < 4; ++j) pk[j] = f2bf(acc[m][nb][j] + bv[nb]);
          *(u16x4*)(Vtws + (size_t)winw * 16384 + d * 256 + rr) = pk;
        }
      }
    }
  }
}

// ---------------- windowed attention (resident K/V, barrier-free loop) ----
// (unchanged — 1 block/window, all K/V in LDS, one barrier, no
// max-subtraction, MFMA row-sums.)
__global__ __launch_bounds__(256, 1)
void attn_win(const u16* __restrict__ Q, const u16* __restrict__ Kws,
              const u16* __restrict__ Vt, u16* __restrict__ Oo)
{
  __shared__ __align__(16) u16 Kl[16384];   // 32 KB: 4 x [64 r x 64 d]
  __shared__ __align__(16) u16 Vl[16384];   // 32 KB: [64 d][256 k]
  __shared__ __align__(16) u16 Pl[16384];   // 32 KB: 4 waves x [64 q x 64 k]
  const int t = threadIdx.x;
  const int wv = t >> 6, l = t & 63, g = l >> 4, r16 = l & 15;
  const int win = blockIdx.x;
  const int b = win >> 8, h = (win >> 4) & 15, wd = win & 15;
  const int s0 = b * 4096 + wd * 256;
  const size_t vwin = (size_t)win * 16384;

  {
    const int rloc = l >> 3, sl = l & 7;
    const u16* ksrc = Kws + (size_t)(s0 + wv * 64 + rloc) * 1024 + h * 64
                      + ((sl ^ rloc) << 3);
#pragma unroll
    for (int j = 0; j < 8; ++j)
      gld16(Kl + wv * 4096 + j * 512, ksrc + (size_t)j * 8 * 1024);
    const int dloc = l >> 5, kcv = (l >> 3) & 3, slv = l & 7;
#pragma unroll
    for (int j = 0; j < 8; ++j){
      int d = wv * 16 + j * 2 + dloc;
      gld16(Vl + (wv * 8 + j) * 512,
            Vt + vwin + (size_t)d * 256 + kcv * 64 + ((slv ^ (d & 7)) << 3));
    }
  }

  bf16x8 aq[4][2];
#pragma unroll
  for (int qm = 0; qm < 4; ++qm)
#pragma unroll
    for (int kk = 0; kk < 2; ++kk)
      aq[qm][kk] = *(const bf16x8*)(Q + (size_t)(s0 + wv * 64 + qm * 16 + r16) * 1024
                                      + h * 64 + kk * 32 + g * 8);

  const f32x4 zero = {0.f, 0.f, 0.f, 0.f};
  f32x4 o[4][4];
  f32x4 lsum[4];
#pragma unroll
  for (int qm = 0; qm < 4; ++qm){
    lsum[qm] = zero;
#pragma unroll
    for (int nd = 0; nd < 4; ++nd) o[qm][nd] = zero;
  }
  bf16x8 onesb;
#pragma unroll
  for (int e = 0; e < 8; ++e) onesb[e] = (__bf16)1.0f;

  const float cl2 = 0.125f * 1.44269504f;

  __syncthreads();

  for (int kc = 0; kc < 4; ++kc){
    f32x4 sc[4][4];
#pragma unroll
    for (int qm = 0; qm < 4; ++qm)
#pragma unroll
      for (int nb = 0; nb < 4; ++nb) sc[qm][nb] = zero;
#pragma unroll
    for (int kk = 0; kk < 2; ++kk){
      bf16x8 kb[4];
#pragma unroll
      for (int nb = 0; nb < 4; ++nb)
        kb[nb] = *(const bf16x8*)(Kl + kc * 4096 + (nb * 16 + r16) * 64
                                  + ((((kk << 2) | g) ^ (r16 & 7)) << 3));
#pragma unroll
      for (int qm = 0; qm < 4; ++qm)
#pragma unroll
        for (int nb = 0; nb < 4; ++nb)
          sc[qm][nb] = mfma16(aq[qm][kk], kb[nb], sc[qm][nb]);
    }

#pragma unroll
    for (int qm = 0; qm < 4; ++qm){
#pragma unroll
      for (int j = 0; j < 4; ++j){
        int q = qm * 16 + g * 4 + j;
        u16* pbase = Pl + wv * 4096 + q * 64;
#pragma unroll
        for (int nb = 0; nb < 4; ++nb){
          float p = __builtin_amdgcn_exp2f(sc[qm][nb][j] * cl2);
          int k = nb * 16 + r16;
          pbase[(k & 7) + (((k >> 3) ^ (q & 7)) << 3)] = f2bf(p);
        }
      }
    }

#pragma unroll
    for (int kc32 = 0; kc32 < 2; ++kc32){
      bf16x8 pa[4], vb[4];
#pragma unroll
      for (int qm = 0; qm < 4; ++qm)
        pa[qm] = *(const bf16x8*)(Pl + wv * 4096 + (qm * 16 + r16) * 64
                                  + ((((kc32 << 2) | g) ^ (r16 & 7)) << 3));
#pragma unroll
      for (int nd = 0; nd < 4; ++nd){
        int d = nd * 16 + r16;
        vb[nd] = *(const bf16x8*)(Vl + d * 256 + kc * 64
                                  + ((((kc32 << 2) | g) ^ (r16 & 7)) << 3));
      }
#pragma unroll
      for (int qm = 0; qm < 4; ++qm){
        lsum[qm] = mfma16(pa[qm], onesb, lsum[qm]);
#pragma unroll
        for (int nd = 0; nd < 4; ++nd)
          o[qm][nd] = mfma16(pa[qm], vb[nd], o[qm][nd]);
      }
    }
  }

#pragma unroll
  for (int qm = 0; qm < 4; ++qm){
#pragma unroll
    for (int j = 0; j < 4; ++j){
      float inv = 1.f / lsum[qm][j];
      int row = s0 + wv * 64 + qm * 16 + g * 4 + j;
#pragma unroll
      for (int nd = 0; nd < 4; ++nd)
        Oo[(size_t)row * 1024 + h * 64 + nd * 16 + r16] = f2bf(o[qm][nd][j] * inv);
    }
  }
}

// ---------------- launch ----------------
extern "C" void kernel_launch(void* const* d_in, const int* in_sizes, int n_in,
                              void* d_out, int out_size, void* d_ws, size_t ws_size,
                              hipStream_t stream)
{
  (void)in_sizes; (void)n_in; (void)out_size; (void)ws_size;
  const float* x  = (const float*)d_in[0];
  const float* Wq = (const float*)d_in[1];
  const float* bq = (const float*)d_in[2];
  const float* Wo = (const float*)d_in[3];
  const float* bo = (const float*)d_in[4];

  char* ws = (char*)d_ws;
  const size_t SZ = (size_t)16384 * 1024 * 2;          // 33.5 MB
  u16* xb  = (u16*)(ws);                               // x bf16, later reused for attn out
  u16* Vt  = (u16*)(ws + SZ);                          // V transposed per window
  u16* wqb = (u16*)(ws + 2 * SZ);                      // W_qkv bf16 (6.29 MB)
  u16* wob = (u16*)(ws + 2 * SZ + 6291456);            // W_out bf16 (2.1 MB)
  u16* Qws = (u16*)d_out;
  u16* Kws = (u16*)d_out + (size_t)16384 * 1024;

  cvt_all<<<2048, 256, 0, stream>>>(x, xb, Wq, wqb, Wo, wob);

  gemm_bt<0><<<dim3(12, 128), 512, 0, stream>>>(xb, wqb, bq, Qws, Kws, Vt, nullptr);

  attn_win<<<1024, 256, 0, stream>>>(Qws, Kws, Vt, xb);

  gemm_bt<1><<<dim3(4, 128), 512, 0, stream>>>(xb, wob, bo,
                                               nullptr, nullptr, nullptr,
                                               (float*)d_out);
}

// Round 13
// 218.614 us; speedup vs baseline: 8.7299x; 1.0387x over previous
//
#include <hip/hip_runtime.h>

typedef unsigned short u16;
typedef __bf16 bf16x8 __attribute__((ext_vector_type(8)));
typedef float f32x4 __attribute__((ext_vector_type(4)));
typedef u16 u16x4 __attribute__((ext_vector_type(4)));

#define DEVI static __device__ __forceinline__

DEVI u16 f2bf(float f){
  unsigned u = __float_as_uint(f);
  u += 0x7FFFu + ((u >> 16) & 1u);
  return (u16)(u >> 16);
}

DEVI f32x4 mfma16(bf16x8 a, bf16x8 b, f32x4 c){
  return __builtin_amdgcn_mfma_f32_16x16x32_bf16(a, b, c, 0, 0, 0);
}

DEVI void gld16(u16* lds, const u16* g){
  __builtin_amdgcn_global_load_lds(
      (const __attribute__((address_space(1))) void*)g,
      (__attribute__((address_space(3))) void*)lds, 16, 0, 0);
}

// ---------------- fp32 -> bf16 convert (all three tensors, one launch) ----
__global__ void cvt_all(const float* __restrict__ x,  u16* __restrict__ xd,
                        const float* __restrict__ wq, u16* __restrict__ wqd,
                        const float* __restrict__ wo, u16* __restrict__ wod){
  constexpr int NX = 4194304;            // 16777216/4
  constexpr int NQ = 786432;             // 3145728/4
  constexpr int NO = 262144;             // 1048576/4
  int i = blockIdx.x * blockDim.x + threadIdx.x;
  int stride = gridDim.x * blockDim.x;
  for (; i < NX + NQ + NO; i += stride){
    const float* s; u16* d; int j;
    if (i < NX){ s = x; d = xd; j = i; }
    else if (i < NX + NQ){ s = wq; d = wqd; j = i - NX; }
    else { s = wo; d = wod; j = i - NX - NQ; }
    float4 v = *(const float4*)(s + (size_t)j * 4);
    u16x4 o = { f2bf(v.x), f2bf(v.y), f2bf(v.z), f2bf(v.w) };
    *(u16x4*)(d + (size_t)j * 4) = o;
  }
}

// ---------------- GEMM: C = A * Bm^T + bias (R9 best config) ----------------
// 256x256 tile, BK=32, 1024 threads (16 waves 4Mx4N, each 64x64 out).
// THREE 32KB LDS buffers (96 KiB), lead-2 staging (race-free: the staging
// buffer's readers finished one full tile ago), ONE barrier per tile,
// counted vmcnt(2) (tile t's 2 loads landed, t+1/t+2's stay in flight;
// never 0 mid-loop). __launch_bounds__(1024,4): VGPR cap 128 (measured 60
// arch + 64 acc). Best of 9 structures tried (R1-R12 ledger): 108 us,
// MfmaUtil 43%, conflicts 0, FETCH ~95 MB.
// Fat-row swizzle (128B fat rows = 2 tile rows, 16B chunk ^= fatrow&7):
// linear gld_lds dest + inverse-swizzled global source + swizzled ds_read.
// MODE 0: QKV epilogue (Q,K row-major bf16; V transposed per-window).
// MODE 1: fp32 store + bias.
template<int MODE>
__global__ __launch_bounds__(1024, 4)
void gemm_bt(const u16* __restrict__ A, const u16* __restrict__ Bm,
             const float* __restrict__ bias,
             u16* __restrict__ Qws, u16* __restrict__ Kws, u16* __restrict__ Vtws,
             float* __restrict__ Cf)
{
  constexpr int K = 1024;
  constexpr int NT = K / 32;                       // 32 K-tiles
  __shared__ __align__(16) u16 lds[3 * 16384];     // 96 KiB (A 16KB + B 16KB per buf)
  const int t = threadIdx.x;
  const int w = t >> 6, l = t & 63, g = l >> 4, r16 = l & 15;
  const int wm = w >> 2, wn = w & 3;               // 4Mx4N wave grid

  // XCD-bijective block swizzle (nwg % 8 == 0 in both modes)
  constexpr int NBX = (MODE == 0) ? 12 : 4;
  constexpr int NWG = NBX * 64;
  const int orig = blockIdx.y * NBX + blockIdx.x;
  const int swzb = (orig & 7) * (NWG >> 3) + (orig >> 3);
  const int row0 = (swzb / NBX) * 256, col0 = (swzb % NBX) * 256;

  const f32x4 zero = {0.f, 0.f, 0.f, 0.f};
  f32x4 acc[4][4];
#pragma unroll
  for (int m = 0; m < 4; ++m)
#pragma unroll
    for (int n = 0; n < 4; ++n) acc[m][n] = zero;

  // ---- staging map: 1024 threads cover the 16KB A region (1024 x 16B
  // chunks) in ONE gld16, ditto B. fat row F = t>>3 (128 per region, 2 tile
  // rows each), slot s = t&7; global logical chunk c = s ^ (F&7);
  // c -> (row parity c>>2, k-chunk c&3)   [rule 21: inverse swizzle on the
  // SOURCE, linear LDS dest].
  const int F = t >> 3;
  const int cc = (t & 7) ^ (F & 7);
  const int strow = 2 * F + (cc >> 2);
  const int stk = (cc & 3) * 8;
  const u16* pA = A + (size_t)(row0 + strow) * K + stk;
  const u16* pB = Bm + (size_t)(col0 + strow) * K + stk;

  auto STAGE = [&](int buf, int kt){
    u16* dst = lds + buf * 16384 + (w << 9);       // wave-uniform base (1KB/wave)
    gld16(dst,        pA + kt);                    // A rows 0..255
    gld16(dst + 8192, pB + kt);                    // B rows 0..255
  };

  // ---- read map (swizzled): fat row R = tilerow>>1, chunk
  // c1 = ((row&1)*4 + g) ^ (R&7); u16 offset = R*64 + c1*8.
  const int c1 = (((r16 & 1) << 2) | g) ^ ((r16 >> 1) & 7);
  const int aoff = (wm * 32 + (r16 >> 1)) * 64 + c1 * 8;
  const int boff = 8192 + (wn * 32 + (r16 >> 1)) * 64 + c1 * 8;

  auto TILECOMP = [&](int buf){
    const u16* base = lds + buf * 16384;
    bf16x8 af[4], bfr[4];
#pragma unroll
    for (int m = 0; m < 4; ++m) af[m] = *(const bf16x8*)(base + aoff + m * 512);
#pragma unroll
    for (int n = 0; n < 4; ++n) bfr[n] = *(const bf16x8*)(base + boff + n * 512);
    __builtin_amdgcn_s_setprio(1);
#pragma unroll
    for (int m = 0; m < 4; ++m)
#pragma unroll
      for (int n = 0; n < 4; ++n)
        acc[m][n] = mfma16(af[m], bfr[n], acc[m][n]);
    __builtin_amdgcn_s_setprio(0);
  };

  // ---- prologue: stage tiles 0 (buf0) and 1 (buf1)
  STAGE(0, 0);
  STAGE(1, 32);
  asm volatile("s_waitcnt vmcnt(2)" ::: "memory");   // tile 0 landed
  __builtin_amdgcn_s_barrier();
  asm volatile("" ::: "memory");

  int cb = 0, sb = 2;
  for (int tt = 0; tt < NT - 2; ++tt){
    STAGE(sb, (tt + 2) * 32);
    TILECOMP(cb);
    asm volatile("s_waitcnt vmcnt(2)" ::: "memory"); // tile tt+1 landed
    __builtin_amdgcn_s_barrier();
    asm volatile("" ::: "memory");
    cb = (cb == 2) ? 0 : cb + 1;
    sb = (sb == 2) ? 0 : sb + 1;
  }
  TILECOMP(cb);                                      // tile NT-2
  cb = (cb == 2) ? 0 : cb + 1;
  asm volatile("s_waitcnt vmcnt(0)" ::: "memory");   // tile NT-1 landed
  __builtin_amdgcn_s_barrier();
  asm volatile("" ::: "memory");
  TILECOMP(cb);                                      // tile NT-1

  // ---- epilogue ----
  float bv[4];
#pragma unroll
  for (int nb = 0; nb < 4; ++nb) bv[nb] = bias[col0 + wn * 64 + nb * 16 + r16];

  if (MODE == 1){
#pragma unroll
    for (int m = 0; m < 4; ++m){
      int row = row0 + wm * 64 + m * 16 + g * 4;
#pragma unroll
      for (int nb = 0; nb < 4; ++nb){
        int n = col0 + wn * 64 + nb * 16 + r16;
#pragma unroll
        for (int j = 0; j < 4; ++j)
          Cf[(size_t)(row + j) * 1024 + n] = acc[m][nb][j] + bv[nb];
      }
    }
  } else {
    const int regn = col0 >> 10;   // uniform per block: 0=Q 1=K 2=V
    if (regn == 0){
#pragma unroll
      for (int m = 0; m < 4; ++m){
        int row = row0 + wm * 64 + m * 16 + g * 4;
#pragma unroll
        for (int nb = 0; nb < 4; ++nb){
          int n = col0 + wn * 64 + nb * 16 + r16;
#pragma unroll
          for (int j = 0; j < 4; ++j)
            Qws[(size_t)(row + j) * 1024 + n] = f2bf(acc[m][nb][j] + bv[nb]);
        }
      }
    } else if (regn == 1){
#pragma unroll
      for (int m = 0; m < 4; ++m){
        int row = row0 + wm * 64 + m * 16 + g * 4;
#pragma unroll
        for (int nb = 0; nb < 4; ++nb){
          int n = col0 + wn * 64 + nb * 16 + r16 - 1024;
#pragma unroll
          for (int j = 0; j < 4; ++j)
            Kws[(size_t)(row + j) * 1024 + n] = f2bf(acc[m][nb][j] + bv[nb]);
        }
      }
    } else {
      // V: store transposed per window: Vt[win][d][rr], win=((b*16+h)*16+wd)
#pragma unroll
      for (int m = 0; m < 4; ++m){
        int row = row0 + wm * 64 + m * 16 + g * 4;
        int bb = row >> 12, s = row & 4095;
        int wdw = s >> 8, rr = s & 255;      // rr multiple of 4
#pragma unroll
        for (int nb = 0; nb < 4; ++nb){
          int n2 = col0 + wn * 64 + nb * 16 + r16 - 2048;
          int hh = n2 >> 6, d = n2 & 63;
          int winw = (bb * 16 + hh) * 16 + wdw;
          u16x4 pk;
#pragma unroll
          for (int j = 0; j < 4; ++j) pk[j] = f2bf(acc[m][nb][j] + bv[nb]);
          *(u16x4*)(Vtws + (size_t)winw * 16384 + d * 256 + rr) = pk;
        }
      }
    }
  }
}

// ---------------- windowed attention (resident K/V, barrier-free loop) ----
// (unchanged — 1 block/window, all K/V in LDS, one barrier, no
// max-subtraction, MFMA row-sums.)
__global__ __launch_bounds__(256, 1)
void attn_win(const u16* __restrict__ Q, const u16* __restrict__ Kws,
              const u16* __restrict__ Vt, u16* __restrict__ Oo)
{
  __shared__ __align__(16) u16 Kl[16384];   // 32 KB: 4 x [64 r x 64 d]
  __shared__ __align__(16) u16 Vl[16384];   // 32 KB: [64 d][256 k]
  __shared__ __align__(16) u16 Pl[16384];   // 32 KB: 4 waves x [64 q x 64 k]
  const int t = threadIdx.x;
  const int wv = t >> 6, l = t & 63, g = l >> 4, r16 = l & 15;
  const int win = blockIdx.x;
  const int b = win >> 8, h = (win >> 4) & 15, wd = win & 15;
  const int s0 = b * 4096 + wd * 256;
  const size_t vwin = (size_t)win * 16384;

  {
    const int rloc = l >> 3, sl = l & 7;
    const u16* ksrc = Kws + (size_t)(s0 + wv * 64 + rloc) * 1024 + h * 64
                      + ((sl ^ rloc) << 3);
#pragma unroll
    for (int j = 0; j < 8; ++j)
      gld16(Kl + wv * 4096 + j * 512, ksrc + (size_t)j * 8 * 1024);
    const int dloc = l >> 5, kcv = (l >> 3) & 3, slv = l & 7;
#pragma unroll
    for (int j = 0; j < 8; ++j){
      int d = wv * 16 + j * 2 + dloc;
      gld16(Vl + (wv * 8 + j) * 512,
            Vt + vwin + (size_t)d * 256 + kcv * 64 + ((slv ^ (d & 7)) << 3));
    }
  }

  bf16x8 aq[4][2];
#pragma unroll
  for (int qm = 0; qm < 4; ++qm)
#pragma unroll
    for (int kk = 0; kk < 2; ++kk)
      aq[qm][kk] = *(const bf16x8*)(Q + (size_t)(s0 + wv * 64 + qm * 16 + r16) * 1024
                                      + h * 64 + kk * 32 + g * 8);

  const f32x4 zero = {0.f, 0.f, 0.f, 0.f};
  f32x4 o[4][4];
  f32x4 lsum[4];
#pragma unroll
  for (int qm = 0; qm < 4; ++qm){
    lsum[qm] = zero;
#pragma unroll
    for (int nd = 0; nd < 4; ++nd) o[qm][nd] = zero;
  }
  bf16x8 onesb;
#pragma unroll
  for (int e = 0; e < 8; ++e) onesb[e] = (__bf16)1.0f;

  const float cl2 = 0.125f * 1.44269504f;

  __syncthreads();

  for (int kc = 0; kc < 4; ++kc){
    f32x4 sc[4][4];
#pragma unroll
    for (int qm = 0; qm < 4; ++qm)
#pragma unroll
      for (int nb = 0; nb < 4; ++nb) sc[qm][nb] = zero;
#pragma unroll
    for (int kk = 0; kk < 2; ++kk){
      bf16x8 kb[4];
#pragma unroll
      for (int nb = 0; nb < 4; ++nb)
        kb[nb] = *(const bf16x8*)(Kl + kc * 4096 + (nb * 16 + r16) * 64
                                  + ((((kk << 2) | g) ^ (r16 & 7)) << 3));
#pragma unroll
      for (int qm = 0; qm < 4; ++qm)
#pragma unroll
        for (int nb = 0; nb < 4; ++nb)
          sc[qm][nb] = mfma16(aq[qm][kk], kb[nb], sc[qm][nb]);
    }

#pragma unroll
    for (int qm = 0; qm < 4; ++qm){
#pragma unroll
      for (int j = 0; j < 4; ++j){
        int q = qm * 16 + g * 4 + j;
        u16* pbase = Pl + wv * 4096 + q * 64;
#pragma unroll
        for (int nb = 0; nb < 4; ++nb){
          float p = __builtin_amdgcn_exp2f(sc[qm][nb][j] * cl2);
          int k = nb * 16 + r16;
          pbase[(k & 7) + (((k >> 3) ^ (q & 7)) << 3)] = f2bf(p);
        }
      }
    }

#pragma unroll
    for (int kc32 = 0; kc32 < 2; ++kc32){
      bf16x8 pa[4], vb[4];
#pragma unroll
      for (int qm = 0; qm < 4; ++qm)
        pa[qm] = *(const bf16x8*)(Pl + wv * 4096 + (qm * 16 + r16) * 64
                                  + ((((kc32 << 2) | g) ^ (r16 & 7)) << 3));
#pragma unroll
      for (int nd = 0; nd < 4; ++nd){
        int d = nd * 16 + r16;
        vb[nd] = *(const bf16x8*)(Vl + d * 256 + kc * 64
                                  + ((((kc32 << 2) | g) ^ (r16 & 7)) << 3));
      }
#pragma unroll
      for (int qm = 0; qm < 4; ++qm){
        lsum[qm] = mfma16(pa[qm], onesb, lsum[qm]);
#pragma unroll
        for (int nd = 0; nd < 4; ++nd)
          o[qm][nd] = mfma16(pa[qm], vb[nd], o[qm][nd]);
      }
    }
  }

#pragma unroll
  for (int qm = 0; qm < 4; ++qm){
#pragma unroll
    for (int j = 0; j < 4; ++j){
      float inv = 1.f / lsum[qm][j];
      int row = s0 + wv * 64 + qm * 16 + g * 4 + j;
#pragma unroll
      for (int nd = 0; nd < 4; ++nd)
        Oo[(size_t)row * 1024 + h * 64 + nd * 16 + r16] = f2bf(o[qm][nd][j] * inv);
    }
  }
}

// ---------------- launch ----------------
extern "C" void kernel_launch(void* const* d_in, const int* in_sizes, int n_in,
                              void* d_out, int out_size, void* d_ws, size_t ws_size,
                              hipStream_t stream)
{
  (void)in_sizes; (void)n_in; (void)out_size; (void)ws_size;
  const float* x  = (const float*)d_in[0];
  const float* Wq = (const float*)d_in[1];
  const float* bq = (const float*)d_in[2];
  const float* Wo = (const float*)d_in[3];
  const float* bo = (const float*)d_in[4];

  char* ws = (char*)d_ws;
  const size_t SZ = (size_t)16384 * 1024 * 2;          // 33.5 MB
  u16* xb  = (u16*)(ws);                               // x bf16, later reused for attn out
  u16* Vt  = (u16*)(ws + SZ);                          // V transposed per window
  u16* wqb = (u16*)(ws + 2 * SZ);                      // W_qkv bf16 (6.29 MB)
  u16* wob = (u16*)(ws + 2 * SZ + 6291456);            // W_out bf16 (2.1 MB)
  u16* Qws = (u16*)d_out;
  u16* Kws = (u16*)d_out + (size_t)16384 * 1024;

  cvt_all<<<2048, 256, 0, stream>>>(x, xb, Wq, wqb, Wo, wob);

  gemm_bt<0><<<dim3(12, 64), 1024, 0, stream>>>(xb, wqb, bq, Qws, Kws, Vt, nullptr);

  attn_win<<<1024, 256, 0, stream>>>(Qws, Kws, Vt, xb);

  gemm_bt<1><<<dim3(4, 64), 1024, 0, stream>>>(xb, wob, bo,
                                               nullptr, nullptr, nullptr,
                                               (float*)d_out);
}